// Round 2
// baseline (679.894 us; speedup 1.0000x reference)
//
#include <hip/hip_runtime.h>

// LocalAttention: B=4, N=4096, DIM=1024, H=16, HD=64, WINDOW=256, EXT=128
// R2: gemm staging via global_load_lds (16B); attention rewritten as
// transposed-S (S^T = K*Q^T) register-resident softmax with zero LDS:
// S^T C-layout == P A-frag layout for mfma_f32_16x16x16f16 PV.

typedef __attribute__((ext_vector_type(8))) short short8;
typedef __attribute__((ext_vector_type(4))) float f32x4;
typedef __attribute__((ext_vector_type(8))) unsigned short ushort8v;
typedef __attribute__((ext_vector_type(4))) unsigned short ushort4v;
typedef __attribute__((ext_vector_type(4))) unsigned int uint4v;
typedef __attribute__((ext_vector_type(4))) _Float16 half4;

#define K_DIM 1024

__device__ __forceinline__ unsigned short f2bf(float f) {
  unsigned int u = __builtin_bit_cast(unsigned int, f);
  u += 0x7FFFu + ((u >> 16) & 1u);
  return (unsigned short)(u >> 16);
}
__device__ __forceinline__ unsigned short f2h(float f) {
  _Float16 h = (_Float16)f;
  return __builtin_bit_cast(unsigned short, h);
}

// ---------------- fp32 -> bf16 convert ----------------
__global__ __launch_bounds__(256) void convf2b(const float* __restrict__ src,
                                               unsigned short* __restrict__ dst, int n4) {
  int i = blockIdx.x * blockDim.x + threadIdx.x;
  if (i >= n4) return;
  f32x4 v = *(const f32x4*)(src + (size_t)i * 4);
  ushort4v o;
  o[0] = f2bf(v[0]); o[1] = f2bf(v[1]); o[2] = f2bf(v[2]); o[3] = f2bf(v[3]);
  *(ushort4v*)(dst + (size_t)i * 4) = o;
}

// ---------------- shared GEMM core: C(128x128) = A * Bw^T ----------------
// Staging via global_load_lds width=16: LDS dest = wave-uniform base + lane*16.
__device__ __forceinline__ void gemm_core(const unsigned short* __restrict__ A,
                                          const unsigned short* __restrict__ Bw,
                                          unsigned short* As, unsigned short* Bs,
                                          int m0, int f0, int tid, f32x4 acc[4][4]) {
  const int lane = tid & 63;
  const int w = tid >> 6;
  const int wm = (tid >> 7) & 1;
  const int wn = (tid >> 6) & 1;
  for (int kk = 0; kk < K_DIM; kk += 32) {
#pragma unroll
    for (int r = 0; r < 2; ++r) {
      int c = tid + r * 256;                  // chunk id: row=c>>2, seg=c&3
      int row = c >> 2, seg = c & 3;
      const unsigned short* ga = A + (size_t)(m0 + row) * K_DIM + kk + seg * 8;
      const unsigned short* gb = Bw + (size_t)(f0 + row) * K_DIM + kk + seg * 8;
      unsigned short* la = As + (size_t)(w * 64 + r * 256) * 8;   // wave-uniform
      unsigned short* lb = Bs + (size_t)(w * 64 + r * 256) * 8;
      __builtin_amdgcn_global_load_lds((const __attribute__((address_space(1))) void*)ga,
                                       (__attribute__((address_space(3))) void*)la, 16, 0, 0);
      __builtin_amdgcn_global_load_lds((const __attribute__((address_space(1))) void*)gb,
                                       (__attribute__((address_space(3))) void*)lb, 16, 0, 0);
    }
    __syncthreads();
    short8 af[4], bf[4];
#pragma unroll
    for (int i = 0; i < 4; ++i)
      af[i] = *(const short8*)&As[(wm * 64 + i * 16 + (lane & 15)) * 32 + (lane >> 4) * 8];
#pragma unroll
    for (int j = 0; j < 4; ++j)
      bf[j] = *(const short8*)&Bs[(wn * 64 + j * 16 + (lane & 15)) * 32 + (lane >> 4) * 8];
#pragma unroll
    for (int i = 0; i < 4; ++i)
#pragma unroll
      for (int j = 0; j < 4; ++j)
        acc[i][j] = __builtin_amdgcn_mfma_f32_16x16x32_bf16(af[i], bf[j], acc[i][j], 0, 0, 0);
    __syncthreads();
  }
}

// ---------------- QKV GEMM + bias + scatter to per-head q/k/v ----------------
// Q,K written bf16 (QK^T mfma is bf16); V written fp16 (PV mfma is f16).
__global__ __launch_bounds__(256) void gemm_qkv(const unsigned short* __restrict__ A,
                                                const unsigned short* __restrict__ Bw,
                                                const float* __restrict__ bias,
                                                unsigned short* __restrict__ q,
                                                unsigned short* __restrict__ k,
                                                unsigned short* __restrict__ v) {
  __shared__ unsigned short As[128 * 32];
  __shared__ unsigned short Bs[128 * 32];
  int m0 = (blockIdx.x & 127) * 128;
  int f0 = (blockIdx.x >> 7) * 128;            // 24 f-tiles
  int tid = threadIdx.x;
  f32x4 acc[4][4] = {};
  gemm_core(A, Bw, As, Bs, m0, f0, tid, acc);
  int lane = tid & 63;
  int wm = (tid >> 7) & 1, wn = (tid >> 6) & 1;
  int which = f0 >> 10;                        // block-uniform (f0 multiple of 128)
  unsigned short* dst = (which == 0) ? q : ((which == 1) ? k : v);
#pragma unroll
  for (int j = 0; j < 4; ++j) {
    int f = f0 + wn * 64 + j * 16 + (lane & 15);
    int hh = (f >> 6) & 15;
    int d = f & 63;
    float bj = bias[f];
#pragma unroll
    for (int i = 0; i < 4; ++i) {
#pragma unroll
      for (int r = 0; r < 4; ++r) {
        int m = m0 + wm * 64 + i * 16 + (lane >> 4) * 4 + r;
        int bb = m >> 12, n = m & 4095;
        float val = acc[i][j][r] + bj;
        dst[((size_t)(bb * 16 + hh) * 4096 + n) * 64 + d] =
            (which == 2) ? f2h(val) : f2bf(val);
      }
    }
  }
}

// ---------------- proj GEMM + bias -> fp32 out ----------------
__global__ __launch_bounds__(256) void gemm_proj(const unsigned short* __restrict__ A,
                                                 const unsigned short* __restrict__ Bw,
                                                 const float* __restrict__ bias,
                                                 float* __restrict__ out) {
  __shared__ unsigned short As[128 * 32];
  __shared__ unsigned short Bs[128 * 32];
  int m0 = (blockIdx.x & 127) * 128;
  int f0 = (blockIdx.x >> 7) * 128;            // 8 f-tiles
  int tid = threadIdx.x;
  f32x4 acc[4][4] = {};
  gemm_core(A, Bw, As, Bs, m0, f0, tid, acc);
  int lane = tid & 63;
  int wm = (tid >> 7) & 1, wn = (tid >> 6) & 1;
#pragma unroll
  for (int j = 0; j < 4; ++j) {
    int f = f0 + wn * 64 + j * 16 + (lane & 15);
    float bj = bias[f];
#pragma unroll
    for (int i = 0; i < 4; ++i) {
#pragma unroll
      for (int r = 0; r < 4; ++r) {
        int m = m0 + wm * 64 + i * 16 + (lane >> 4) * 4 + r;
        out[(size_t)m * 1024 + f] = acc[i][j][r] + bj;
      }
    }
  }
}

// ---------------- V transpose: (B,H,4096,64) -> (B,H,64,4096) ----------------
__global__ __launch_bounds__(256) void transpose_v(const unsigned short* __restrict__ v,
                                                   unsigned short* __restrict__ vt) {
  __shared__ unsigned short tile[64][72];
  int bid = blockIdx.x;
  int bh = bid >> 6;
  int n0 = (bid & 63) * 64;
  int tid = threadIdx.x;
#pragma unroll
  for (int r = 0; r < 2; ++r) {
    int c = tid + r * 256;
    int row = c >> 3, col8 = (c & 7) * 8;
    uint4v dv = *(const uint4v*)&v[((size_t)bh * 4096 + n0 + row) * 64 + col8];
    *(uint4v*)&tile[row][col8] = dv;
  }
  __syncthreads();
#pragma unroll
  for (int r = 0; r < 2; ++r) {
    int c = tid + r * 256;
    int d = c >> 3, n8 = (c & 7) * 8;
    ushort8v o;
#pragma unroll
    for (int ii = 0; ii < 8; ++ii) o[ii] = tile[n8 + ii][d];
    *(ushort8v*)&vt[((size_t)bh * 64 + d) * 4096 + n0 + n8] = o;
  }
}

// ---------------- windowed attention v2: register-resident, zero LDS ----------
// Block = 4 independent waves; wave owns 16 queries x 512-key window.
// S^T = K*Q^T (mfma 16x16x32 bf16): C-layout row=key=(lane>>4)*4+r, col=q=lane&15.
// That IS the A-frag layout of P for mfma_f32_16x16x16f16 -> PV with no LDS.
__global__ __launch_bounds__(256) void attn2(const unsigned short* __restrict__ Q,
                                             const unsigned short* __restrict__ Kb,
                                             const unsigned short* __restrict__ Vt,
                                             unsigned short* __restrict__ Ao) {
  int bid = blockIdx.x;                        // 64 bh * 64 qblocks
  int qb = bid & 63;
  int bh = bid >> 6;
  int b = bh >> 4, h = bh & 15;
  int tid = threadIdx.x, lane = tid & 63, w = tid >> 6;
  int q0 = qb * 64 + w * 16;                   // wave's 16 queries
  int g = qb >> 2;
  int kst = g * 256 - 128;
  // window-edge tiles are wave-uniformly fully-invalid: skip them entirely
  int ntlo = (g == 0) ? 8 : 0;
  int nthi = (g == 15) ? 24 : 32;
  const size_t base = (size_t)bh * 4096 * 64;
  const int q15 = lane & 15, quad = lane >> 4;

  // Q B-frags: B[k=d][n=q] -> lane holds q=lane&15, d=quad*8+j+32s
  short8 bq[2];
#pragma unroll
  for (int s = 0; s < 2; ++s)
    bq[s] = *(const short8*)&Q[base + (size_t)(q0 + q15) * 64 + s * 32 + quad * 8];

  f32x4 sacc[32];
#pragma unroll
  for (int nt = 0; nt < 32; ++nt) sacc[nt] = (f32x4){0.f, 0.f, 0.f, 0.f};

  // ---- QK^T (transposed): sacc[nt] = K_tile * Q^T ----
#pragma unroll
  for (int nt = 0; nt < 32; ++nt) {
    if (nt < ntlo || nt >= nthi) continue;
    const unsigned short* kp =
        &Kb[base + (size_t)(kst + nt * 16 + q15) * 64 + quad * 8];
    short8 ak0 = *(const short8*)kp;
    short8 ak1 = *(const short8*)(kp + 32);
    sacc[nt] = __builtin_amdgcn_mfma_f32_16x16x32_bf16(ak0, bq[0], sacc[nt], 0, 0, 0);
    sacc[nt] = __builtin_amdgcn_mfma_f32_16x16x32_bf16(ak1, bq[1], sacc[nt], 0, 0, 0);
  }

  // ---- per-query max: lane holds only its own query's scores ----
  float mx = -1e30f;
#pragma unroll
  for (int nt = 0; nt < 32; ++nt) {
    if (nt < ntlo || nt >= nthi) continue;
#pragma unroll
    for (int r = 0; r < 4; ++r) mx = fmaxf(mx, sacc[nt][r]);
  }
  mx = fmaxf(mx, __shfl_xor(mx, 16, 64));
  mx = fmaxf(mx, __shfl_xor(mx, 32, 64));
  const float m8 = mx * 0.125f;                // SCALE = 1/8

  // ---- exp + PV fused ----
  float sum = 0.f;
  f32x4 oacc[4];
#pragma unroll
  for (int dt = 0; dt < 4; ++dt) oacc[dt] = (f32x4){0.f, 0.f, 0.f, 0.f};

#pragma unroll
  for (int nt = 0; nt < 32; ++nt) {
    if (nt < ntlo || nt >= nthi) continue;
    float p0 = __expf(sacc[nt][0] * 0.125f - m8);
    float p1 = __expf(sacc[nt][1] * 0.125f - m8);
    float p2 = __expf(sacc[nt][2] * 0.125f - m8);
    float p3 = __expf(sacc[nt][3] * 0.125f - m8);
    sum += (p0 + p1) + (p2 + p3);
    half4 pk;
    pk[0] = (_Float16)p0; pk[1] = (_Float16)p1;
    pk[2] = (_Float16)p2; pk[3] = (_Float16)p3;
    int krow = kst + nt * 16 + quad * 4;
#pragma unroll
    for (int dt = 0; dt < 4; ++dt) {
      half4 bv = *(const half4*)&Vt[((size_t)bh * 64 + dt * 16 + q15) * 4096 + krow];
      oacc[dt] = __builtin_amdgcn_mfma_f32_16x16x16f16(pk, bv, oacc[dt], 0, 0, 0);
    }
  }
  sum += __shfl_xor(sum, 16, 64);
  sum += __shfl_xor(sum, 32, 64);
  float linv = 1.0f / sum;

  // ---- normalize + store: O C-layout row=q=quad*4+r, col=d=q15+16dt ----
  float li[4];
#pragma unroll
  for (int r = 0; r < 4; ++r) li[r] = __shfl(linv, quad * 4 + r, 64);
#pragma unroll
  for (int dt = 0; dt < 4; ++dt) {
#pragma unroll
    for (int r = 0; r < 4; ++r) {
      float o = oacc[dt][r] * li[r];
      Ao[(size_t)(b * 4096 + q0 + quad * 4 + r) * 1024 + h * 64 + dt * 16 + q15] = f2bf(o);
    }
  }
}

// ---------------- host ----------------
extern "C" void kernel_launch(void* const* d_in, const int* in_sizes, int n_in,
                              void* d_out, int out_size, void* d_ws, size_t ws_size,
                              hipStream_t stream) {
  const float* x = (const float*)d_in[0];
  const float* w_qkv = (const float*)d_in[1];
  const float* b_qkv = (const float*)d_in[2];
  const float* w_proj = (const float*)d_in[3];
  const float* b_proj = (const float*)d_in[4];
  float* out = (float*)d_out;

  unsigned short* ws = (unsigned short*)d_ws;
  unsigned short* xb = ws;                       // 16777216 elems (reused as vt later)
  unsigned short* wqkvb = ws + 16777216;         // 3145728
  unsigned short* wprojb = ws + 19922944;        // 1048576
  unsigned short* qb = ws + 20971520;            // 16777216
  unsigned short* kb = ws + 37748736;            // 16777216
  unsigned short* vb = ws + 54525952;            // 16777216 (fp16)
  unsigned short* attnb = ws + 71303168;         // 16777216
  unsigned short* vtb = xb;                      // alias: xb dead after gemm_qkv

  convf2b<<<16384, 256, 0, stream>>>(x, xb, 16777216 / 4);
  convf2b<<<3072, 256, 0, stream>>>(w_qkv, wqkvb, 3145728 / 4);
  convf2b<<<1024, 256, 0, stream>>>(w_proj, wprojb, 1048576 / 4);
  gemm_qkv<<<128 * 24, 256, 0, stream>>>(xb, wqkvb, b_qkv, qb, kb, vb);
  transpose_v<<<4096, 256, 0, stream>>>(vb, vtb);
  attn2<<<4096, 256, 0, stream>>>(qb, kb, vtb, attnb);
  gemm_proj<<<128 * 8, 256, 0, stream>>>(attnb, wprojb, b_proj, out);
}

// Round 3
// 425.864 us; speedup vs baseline: 1.5965x; 1.5965x over previous
//
#include <hip/hip_runtime.h>

// LocalAttention: B=4, N=4096, DIM=1024, H=16, HD=64, WINDOW=256, EXT=128
// R3: attention = chunked two-pass, transposed-S, K/V staged to LDS via
// global_load_lds with XOR-swizzled layout (swizzle on global source side),
// S packed fp16 in regs. GEMM LDS also XOR-swizzled.

typedef __attribute__((ext_vector_type(8))) short short8;
typedef __attribute__((ext_vector_type(4))) float f32x4;
typedef __attribute__((ext_vector_type(8))) unsigned short ushort8v;
typedef __attribute__((ext_vector_type(4))) unsigned short ushort4v;
typedef __attribute__((ext_vector_type(4))) unsigned int uint4v;
typedef __attribute__((ext_vector_type(4))) _Float16 half4;

#define K_DIM 1024

__device__ __forceinline__ unsigned short f2bf(float f) {
  unsigned int u = __builtin_bit_cast(unsigned int, f);
  u += 0x7FFFu + ((u >> 16) & 1u);
  return (unsigned short)(u >> 16);
}
__device__ __forceinline__ unsigned short f2h(float f) {
  _Float16 h = (_Float16)f;
  return __builtin_bit_cast(unsigned short, h);
}
__device__ __forceinline__ void gload_lds(const unsigned short* g, unsigned short* l) {
  __builtin_amdgcn_global_load_lds((const __attribute__((address_space(1))) void*)g,
                                   (__attribute__((address_space(3))) void*)l, 16, 0, 0);
}

// ---------------- fp32 -> bf16 convert ----------------
__global__ __launch_bounds__(256) void convf2b(const float* __restrict__ src,
                                               unsigned short* __restrict__ dst, int n4) {
  int i = blockIdx.x * blockDim.x + threadIdx.x;
  if (i >= n4) return;
  f32x4 v = *(const f32x4*)(src + (size_t)i * 4);
  ushort4v o;
  o[0] = f2bf(v[0]); o[1] = f2bf(v[1]); o[2] = f2bf(v[2]); o[3] = f2bf(v[3]);
  *(ushort4v*)(dst + (size_t)i * 4) = o;
}

// ---------------- shared GEMM core: C(128x128) = A * Bw^T ----------------
// global_load_lds width=16 staging; XOR swizzle seg^=(row&3) on global side,
// frag reads use seg = quad ^ (q15&3): 8-way bank conflict -> 4-way.
__device__ __forceinline__ void gemm_core(const unsigned short* __restrict__ A,
                                          const unsigned short* __restrict__ Bw,
                                          unsigned short* As, unsigned short* Bs,
                                          int m0, int f0, int tid, f32x4 acc[4][4]) {
  const int lane = tid & 63;
  const int w = tid >> 6;
  const int wm = (tid >> 7) & 1;
  const int wn = (tid >> 6) & 1;
  const int q15 = lane & 15, quad = lane >> 4;
  const int sw = q15 & 3;
  for (int kk = 0; kk < K_DIM; kk += 32) {
#pragma unroll
    for (int r = 0; r < 2; ++r) {
      int c = tid + r * 256;
      int row = c >> 2, s = c & 3;
      int gs = s ^ (row & 3);
      const unsigned short* ga = A + (size_t)(m0 + row) * K_DIM + kk + gs * 8;
      const unsigned short* gb = Bw + (size_t)(f0 + row) * K_DIM + kk + gs * 8;
      unsigned short* la = As + (size_t)(w * 64 + r * 256) * 8;
      unsigned short* lb = Bs + (size_t)(w * 64 + r * 256) * 8;
      gload_lds(ga, la);
      gload_lds(gb, lb);
    }
    __syncthreads();
    short8 af[4], bf[4];
#pragma unroll
    for (int i = 0; i < 4; ++i)
      af[i] = *(const short8*)&As[(wm * 64 + i * 16 + q15) * 32 + (quad ^ sw) * 8];
#pragma unroll
    for (int j = 0; j < 4; ++j)
      bf[j] = *(const short8*)&Bs[(wn * 64 + j * 16 + q15) * 32 + (quad ^ sw) * 8];
#pragma unroll
    for (int i = 0; i < 4; ++i)
#pragma unroll
      for (int j = 0; j < 4; ++j)
        acc[i][j] = __builtin_amdgcn_mfma_f32_16x16x32_bf16(af[i], bf[j], acc[i][j], 0, 0, 0);
    __syncthreads();
  }
}

// ---------------- QKV GEMM + bias + scatter to per-head q/k/v ----------------
__global__ __launch_bounds__(256) void gemm_qkv(const unsigned short* __restrict__ A,
                                                const unsigned short* __restrict__ Bw,
                                                const float* __restrict__ bias,
                                                unsigned short* __restrict__ q,
                                                unsigned short* __restrict__ k,
                                                unsigned short* __restrict__ v) {
  __shared__ unsigned short As[128 * 32];
  __shared__ unsigned short Bs[128 * 32];
  int m0 = (blockIdx.x & 127) * 128;
  int f0 = (blockIdx.x >> 7) * 128;            // 24 f-tiles
  int tid = threadIdx.x;
  f32x4 acc[4][4] = {};
  gemm_core(A, Bw, As, Bs, m0, f0, tid, acc);
  int lane = tid & 63;
  int wm = (tid >> 7) & 1, wn = (tid >> 6) & 1;
  int which = f0 >> 10;                        // block-uniform
  unsigned short* dst = (which == 0) ? q : ((which == 1) ? k : v);
#pragma unroll
  for (int j = 0; j < 4; ++j) {
    int f = f0 + wn * 64 + j * 16 + (lane & 15);
    int hh = (f >> 6) & 15;
    int d = f & 63;
    float bj = bias[f];
#pragma unroll
    for (int i = 0; i < 4; ++i) {
#pragma unroll
      for (int r = 0; r < 4; ++r) {
        int m = m0 + wm * 64 + i * 16 + (lane >> 4) * 4 + r;
        int bb = m >> 12, n = m & 4095;
        float val = acc[i][j][r] + bj;
        dst[((size_t)(bb * 16 + hh) * 4096 + n) * 64 + d] =
            (which == 2) ? f2h(val) : f2bf(val);
      }
    }
  }
}

// ---------------- proj GEMM + bias -> fp32 out ----------------
__global__ __launch_bounds__(256) void gemm_proj(const unsigned short* __restrict__ A,
                                                 const unsigned short* __restrict__ Bw,
                                                 const float* __restrict__ bias,
                                                 float* __restrict__ out) {
  __shared__ unsigned short As[128 * 32];
  __shared__ unsigned short Bs[128 * 32];
  int m0 = (blockIdx.x & 127) * 128;
  int f0 = (blockIdx.x >> 7) * 128;            // 8 f-tiles
  int tid = threadIdx.x;
  f32x4 acc[4][4] = {};
  gemm_core(A, Bw, As, Bs, m0, f0, tid, acc);
  int lane = tid & 63;
  int wm = (tid >> 7) & 1, wn = (tid >> 6) & 1;
#pragma unroll
  for (int j = 0; j < 4; ++j) {
    int f = f0 + wn * 64 + j * 16 + (lane & 15);
    float bj = bias[f];
#pragma unroll
    for (int i = 0; i < 4; ++i) {
#pragma unroll
      for (int r = 0; r < 4; ++r) {
        int m = m0 + wm * 64 + i * 16 + (lane >> 4) * 4 + r;
        out[(size_t)m * 1024 + f] = acc[i][j][r] + bj;
      }
    }
  }
}

// ---------------- V transpose: (B,H,4096,64) -> (B,H,64,4096) fp16 ----------
__global__ __launch_bounds__(256) void transpose_v(const unsigned short* __restrict__ v,
                                                   unsigned short* __restrict__ vt) {
  __shared__ unsigned short tile[64][72];
  int bid = blockIdx.x;
  int bh = bid >> 6;
  int n0 = (bid & 63) * 64;
  int tid = threadIdx.x;
#pragma unroll
  for (int r = 0; r < 2; ++r) {
    int c = tid + r * 256;
    int row = c >> 3, col8 = (c & 7) * 8;
    uint4v dv = *(const uint4v*)&v[((size_t)bh * 4096 + n0 + row) * 64 + col8];
    *(uint4v*)&tile[row][col8] = dv;
  }
  __syncthreads();
#pragma unroll
  for (int r = 0; r < 2; ++r) {
    int c = tid + r * 256;
    int d = c >> 3, n8 = (c & 7) * 8;
    ushort8v o;
#pragma unroll
    for (int ii = 0; ii < 8; ++ii) o[ii] = tile[n8 + ii][d];
    *(ushort8v*)&vt[((size_t)bh * 64 + d) * 4096 + n0 + n8] = o;
  }
}

// ---------------- windowed attention v3 ----------------
// Block = 4 waves; wave owns 16 queries. 512-key window in 4 chunks of 128.
// Pass A: stage K chunks (LDS, dbuf, swizzled) -> S^T tiles -> scaled fp16 in regs.
// Pass B: stage V^T chunks -> exp -> PV (mfma 16x16x16f16) -> normalize, store.
__global__ __launch_bounds__(256) void attn3(const unsigned short* __restrict__ Q,
                                             const unsigned short* __restrict__ Kb,
                                             const unsigned short* __restrict__ Vt,
                                             unsigned short* __restrict__ Ao) {
  __shared__ unsigned short lds2[2][8192];     // 2 x 16KB

  int bid = blockIdx.x;                        // 64 bh * 64 qblocks
  int qb = bid & 63;
  int bh = bid >> 6;
  int b = bh >> 4, h = bh & 15;
  int tid = threadIdx.x, lane = tid & 63, w = tid >> 6;
  int q0 = qb * 64 + w * 16;
  int g = qb >> 2;
  int kst = g * 256 - 128;
  const size_t base = (size_t)bh * 4096 * 64;
  const int q15 = lane & 15, quad = lane >> 4;

  // Q B-frags: lane holds q=q15, d=quad*8+j (+32s)
  short8 bq[2];
#pragma unroll
  for (int s = 0; s < 2; ++s)
    bq[s] = *(const short8*)&Q[base + (size_t)(q0 + q15) * 64 + s * 32 + quad * 8];

  // ---- Pass A: S^T = K * Q^T, packed scaled fp16 in spk ----
  half4 spk[32];
  float mx = -1e30f;

  auto stageK = [&](int c, int buf) {
    int kb = kst + c * 128;
    kb = min(max(kb, 0), 4096 - 128);
    const unsigned short* Kg = Kb + base + (size_t)kb * 64;
#pragma unroll
    for (int i = 0; i < 4; ++i) {
      int slot = tid + i * 256;
      int row = slot >> 3, s = slot & 7;
      int gs = s ^ (row & 7);
      gload_lds(Kg + (size_t)row * 64 + gs * 8, &lds2[buf][(w * 64 + i * 256) * 8]);
    }
  };

  stageK(0, 0);
#pragma unroll
  for (int c = 0; c < 4; ++c) {
    __syncthreads();
    if (c < 3) stageK(c + 1, (c + 1) & 1);
    const unsigned short* Kc = lds2[c & 1];
    int r7 = q15 & 7;
#pragma unroll
    for (int nt = 0; nt < 8; ++nt) {
      int t = c * 8 + nt;
      int ky = kst + c * 128 + nt * 16;
      bool valid = (ky >= 0) && (ky < 4096);
      if (valid) {
        int sg0 = quad ^ r7;
        const unsigned short* kr = &Kc[(nt * 16 + q15) * 64];
        short8 ak0 = *(const short8*)&kr[sg0 * 8];
        short8 ak1 = *(const short8*)&kr[(sg0 ^ 4) * 8];
        f32x4 sa = {0.f, 0.f, 0.f, 0.f};
        sa = __builtin_amdgcn_mfma_f32_16x16x32_bf16(ak0, bq[0], sa, 0, 0, 0);
        sa = __builtin_amdgcn_mfma_f32_16x16x32_bf16(ak1, bq[1], sa, 0, 0, 0);
        float s0 = sa[0] * 0.125f, s1 = sa[1] * 0.125f;
        float s2 = sa[2] * 0.125f, s3 = sa[3] * 0.125f;
        mx = fmaxf(mx, fmaxf(fmaxf(s0, s1), fmaxf(s2, s3)));
        half4 pk;
        pk[0] = (_Float16)s0; pk[1] = (_Float16)s1;
        pk[2] = (_Float16)s2; pk[3] = (_Float16)s3;
        spk[t] = pk;
      } else {
        spk[t] = (half4){(_Float16)0.f, (_Float16)0.f, (_Float16)0.f, (_Float16)0.f};
      }
    }
  }
  // per-query max: lane's scores all belong to query q0+q15
  mx = fmaxf(mx, __shfl_xor(mx, 16, 64));
  mx = fmaxf(mx, __shfl_xor(mx, 32, 64));

  // ---- Pass B: exp + PV ----
  auto stageV = [&](int c, int buf) {
    int kb = kst + c * 128;
    kb = min(max(kb, 0), 4096 - 128);
    const unsigned short* Vg = Vt + (size_t)bh * 64 * 4096 + kb;
#pragma unroll
    for (int i = 0; i < 4; ++i) {
      int slot = tid + i * 256;
      int d = slot >> 4, s = slot & 15;
      int gs = s ^ (d & 15);
      gload_lds(Vg + (size_t)d * 4096 + gs * 8, &lds2[buf][(w * 64 + i * 256) * 8]);
    }
  };

  float sum = 0.f;
  f32x4 oacc[4];
#pragma unroll
  for (int dt = 0; dt < 4; ++dt) oacc[dt] = (f32x4){0.f, 0.f, 0.f, 0.f};

  stageV(0, 0);
#pragma unroll
  for (int c = 0; c < 4; ++c) {
    __syncthreads();
    if (c < 3) stageV(c + 1, (c + 1) & 1);
    const unsigned short* Vc = lds2[c & 1];
#pragma unroll
    for (int nt = 0; nt < 8; ++nt) {
      int t = c * 8 + nt;
      int ky = kst + c * 128 + nt * 16;
      bool valid = (ky >= 0) && (ky < 4096);
      if (!valid) continue;
      half4 sp = spk[t];
      float p0 = __expf((float)sp[0] - mx);
      float p1 = __expf((float)sp[1] - mx);
      float p2 = __expf((float)sp[2] - mx);
      float p3 = __expf((float)sp[3] - mx);
      sum += (p0 + p1) + (p2 + p3);
      half4 pk;
      pk[0] = (_Float16)p0; pk[1] = (_Float16)p1;
      pk[2] = (_Float16)p2; pk[3] = (_Float16)p3;
      int sgb = 2 * nt + (quad >> 1);
      int eo = (quad & 1) * 4;
#pragma unroll
      for (int dt = 0; dt < 4; ++dt) {
        int d = dt * 16 + q15;
        half4 bv = *(const half4*)&Vc[d * 128 + ((sgb ^ q15) * 8) + eo];
        oacc[dt] = __builtin_amdgcn_mfma_f32_16x16x16f16(pk, bv, oacc[dt], 0, 0, 0);
      }
    }
  }
  sum += __shfl_xor(sum, 16, 64);
  sum += __shfl_xor(sum, 32, 64);
  float linv = 1.0f / sum;

  // normalize + store: O C-layout row=q=quad*4+r, col=d=q15+16dt
  float li[4];
#pragma unroll
  for (int r = 0; r < 4; ++r) li[r] = __shfl(linv, quad * 4 + r, 64);
#pragma unroll
  for (int dt = 0; dt < 4; ++dt) {
#pragma unroll
    for (int r = 0; r < 4; ++r) {
      float o = oacc[dt][r] * li[r];
      Ao[(size_t)(b * 4096 + q0 + quad * 4 + r) * 1024 + h * 64 + dt * 16 + q15] = f2bf(o);
    }
  }
}

// ---------------- host ----------------
extern "C" void kernel_launch(void* const* d_in, const int* in_sizes, int n_in,
                              void* d_out, int out_size, void* d_ws, size_t ws_size,
                              hipStream_t stream) {
  const float* x = (const float*)d_in[0];
  const float* w_qkv = (const float*)d_in[1];
  const float* b_qkv = (const float*)d_in[2];
  const float* w_proj = (const float*)d_in[3];
  const float* b_proj = (const float*)d_in[4];
  float* out = (float*)d_out;

  unsigned short* ws = (unsigned short*)d_ws;
  unsigned short* xb = ws;                       // 16777216 elems (reused as vt later)
  unsigned short* wqkvb = ws + 16777216;         // 3145728
  unsigned short* wprojb = ws + 19922944;        // 1048576
  unsigned short* qb = ws + 20971520;            // 16777216
  unsigned short* kb = ws + 37748736;            // 16777216
  unsigned short* vb = ws + 54525952;            // 16777216 (fp16)
  unsigned short* attnb = ws + 71303168;         // 16777216
  unsigned short* vtb = xb;                      // alias: xb dead after gemm_qkv

  convf2b<<<16384, 256, 0, stream>>>(x, xb, 16777216 / 4);
  convf2b<<<3072, 256, 0, stream>>>(w_qkv, wqkvb, 3145728 / 4);
  convf2b<<<1024, 256, 0, stream>>>(w_proj, wprojb, 1048576 / 4);
  gemm_qkv<<<128 * 24, 256, 0, stream>>>(xb, wqkvb, b_qkv, qb, kb, vb);
  transpose_v<<<4096, 256, 0, stream>>>(vb, vtb);
  attn3<<<4096, 256, 0, stream>>>(qb, kb, vtb, attnb);
  gemm_proj<<<128 * 8, 256, 0, stream>>>(attnb, wprojb, b_proj, out);
}